// Round 6
// baseline (410.362 us; speedup 1.0000x reference)
//
#include <hip/hip_runtime.h>

#define EPS_C 0.05f
#define BLOCK 256
#define SUBT 2                    /* sub-tiles per block */
#define CHUNK (SUBT * 4096)       /* 8192 elems per block, 32 per thread */

typedef float f4 __attribute__((ext_vector_type(4)));

// Build the 6-entry change table into LDS (thread 0 only; caller syncs).
__device__ __forceinline__ void build_table(const float* bd_p, const float* d_p,
                                            const float* s_p, const float* inc_p,
                                            const float* bi_p, float* cs) {
  if (threadIdx.x == 0) {
    float bd = *bd_p, d = *d_p, s = *s_p, inc = *inc_p, bi = *bi_p;
    cs[0] = 0.0f;                                       // cat 0 (unused)
    cs[1] = fminf(bd, fminf(0.0f, d)) - EPS_C;          // big decrease
    cs[2] = fminf(fmaxf(d, bd + EPS_C), -EPS_C);        // decrease (clip)
    cs[3] = s;                                          // same
    cs[4] = fminf(fmaxf(inc, EPS_C), bi - EPS_C);       // increase (clip)
    cs[5] = fmaxf(bi, fmaxf(0.0f, inc) + EPS_C);        // big increase
    cs[6] = 0.0f; cs[7] = 0.0f;
  }
}

// Pass 1: per-block sum + re-pack categories to 4 bits/elem in global ws.
// Sub-tile j: thread t reads 4 consecutive int4 (64 B), emits one uint2.
__global__ __launch_bounds__(BLOCK) void k_reduce_pack(
    const int* __restrict__ ann, const float* bd, const float* d,
    const float* s, const float* inc, const float* bi,
    uint2* __restrict__ packed, float* __restrict__ sums) {
  __shared__ float cs[8];
  __shared__ float wsum[BLOCK / 64];
  build_table(bd, d, s, inc, bi, cs);
  __syncthreads();

  const int b = blockIdx.x, t = threadIdx.x;
  const int4* in4 = (const int4*)(ann + (size_t)b * CHUNK);

  float sum = 0.0f;
#pragma unroll
  for (int j = 0; j < SUBT; ++j) {
    unsigned int w0 = 0u, w1 = 0u;
#pragma unroll
    for (int i = 0; i < 4; ++i) {
      int4 v = in4[j * 1024 + t * 4 + i];
      sum += cs[v.x] + cs[v.y] + cs[v.z] + cs[v.w];
      unsigned int nib = (unsigned)v.x | ((unsigned)v.y << 4) |
                         ((unsigned)v.z << 8) | ((unsigned)v.w << 12);
      if (i < 2) w0 |= nib << ((i & 1) * 16);
      else       w1 |= nib << ((i & 1) * 16);
    }
    packed[(size_t)b * (SUBT * BLOCK) + j * BLOCK + t] = make_uint2(w0, w1);
  }

#pragma unroll
  for (int off = 32; off >= 1; off >>= 1) sum += __shfl_down(sum, off, 64);
  const int lane = t & 63, wid = t >> 6;
  if (lane == 0) wsum[wid] = sum;
  __syncthreads();
  if (t == 0) sums[b] = wsum[0] + wsum[1] + wsum[2] + wsum[3];
}

// Pass 2: block b reduces sums[0..b) for its offset (pack loads issued first,
// in flight during the reduce), decodes, block-scans, writes with nt stores.
__global__ __launch_bounds__(BLOCK) void k_scan_out(
    const uint2* __restrict__ packed, const float* __restrict__ sums,
    const float* __restrict__ origin, const float* bd, const float* d,
    const float* s, const float* inc, const float* bi,
    float* __restrict__ out, int nb) {
  __shared__ float cs[8];
  __shared__ float wsum[BLOCK / 64];
  __shared__ float s_base;
  build_table(bd, d, s, inc, bi, cs);
  __syncthreads();

  const int b = blockIdx.x, t = threadIdx.x;
  const int lane = t & 63, wid = t >> 6;

  // Issue pack loads first so they're in flight during the sums reduce.
  uint2 w[SUBT];
#pragma unroll
  for (int j = 0; j < SUBT; ++j)
    w[j] = packed[(size_t)b * (SUBT * BLOCK) + j * BLOCK + t];

  // Block offset: reduce predecessor sums (<= nb/BLOCK = 16 iterations).
  float p = 0.0f;
  for (int i = t; i < b; i += BLOCK) p += sums[i];
#pragma unroll
  for (int off = 32; off >= 1; off >>= 1) p += __shfl_down(p, off, 64);
  if (lane == 0) wsum[wid] = p;
  __syncthreads();
  if (t == 0) s_base = *origin + wsum[0] + wsum[1] + wsum[2] + wsum[3];
  __syncthreads();

  float carry = s_base;
#pragma unroll
  for (int j = 0; j < SUBT; ++j) {
    // Decode 16 categories from one uint2.
    float vals[16];
#pragma unroll
    for (int k = 0; k < 8; ++k) vals[k] = cs[(w[j].x >> (4 * k)) & 0xF];
#pragma unroll
    for (int k = 0; k < 8; ++k) vals[8 + k] = cs[(w[j].y >> (4 * k)) & 0xF];

    float run = 0.0f;
#pragma unroll
    for (int i = 0; i < 16; ++i) run += vals[i];

    float x = run;  // inclusive wave scan of per-thread totals
#pragma unroll
    for (int off = 1; off < 64; off <<= 1) {
      float y = __shfl_up(x, off, 64);
      if (lane >= off) x += y;
    }
    __syncthreads();  // prior wsum/s_base reads are done
    if (lane == 63) wsum[wid] = x;
    __syncthreads();
    float wexcl = 0.0f, tot = 0.0f;
#pragma unroll
    for (int i = 0; i < BLOCK / 64; ++i) {
      float wv = wsum[i];
      if (i < wid) wexcl += wv;
      tot += wv;
    }
    const float off0 = carry + wexcl + (x - run);  // thread-exclusive prefix

    f4* out4 = (f4*)(out + (size_t)b * CHUNK + j * 4096);
    float r = off0;
#pragma unroll
    for (int i = 0; i < 4; ++i) {
      f4 o;
      o.x = r; r += vals[i * 4 + 0];
      o.y = r; r += vals[i * 4 + 1];
      o.z = r; r += vals[i * 4 + 2];
      o.w = r; r += vals[i * 4 + 3];
      __builtin_nontemporal_store(o, &out4[t * 4 + i]);  // don't pollute L3
    }
    carry += tot;

    if (b == nb - 1 && t == BLOCK - 1 && j == SUBT - 1)
      out[(size_t)nb * CHUNK] = r;  // out[N] = origin + total sum
  }
}

extern "C" void kernel_launch(void* const* d_in, const int* in_sizes, int n_in,
                              void* d_out, int out_size, void* d_ws, size_t ws_size,
                              hipStream_t stream) {
  const int*   ann    = (const int*)d_in[0];
  const float* origin = (const float*)d_in[1];
  const float* bd     = (const float*)d_in[2];
  const float* dw     = (const float*)d_in[3];
  const float* sw     = (const float*)d_in[4];
  const float* inc    = (const float*)d_in[5];
  const float* bi     = (const float*)d_in[6];
  float* out = (float*)d_out;

  const int N  = in_sizes[0];   // 2^25, divisible by CHUNK
  const int nb = N / CHUNK;     // 4096

  float* sums   = (float*)d_ws;                      // nb floats (16 KB)
  uint2* packed = (uint2*)((char*)d_ws + 32768);     // nb*512 uint2 (16.8 MB)

  k_reduce_pack<<<nb, BLOCK, 0, stream>>>(ann, bd, dw, sw, inc, bi, packed, sums);
  k_scan_out<<<nb, BLOCK, 0, stream>>>(packed, sums, origin, bd, dw, sw, inc, bi,
                                       out, nb);
}

// Round 7
// 272.152 us; speedup vs baseline: 1.5078x; 1.5078x over previous
//
#include <hip/hip_runtime.h>

#define EPS_C 0.05f
#define BLOCK 256
#define SUBT 2                    /* sub-tiles per block */
#define CHUNK (SUBT * 4096)       /* 8192 elems per block, 32 per thread */

// Build the 6-entry change table into LDS (thread 0 only; caller syncs).
__device__ __forceinline__ void build_table(const float* bd_p, const float* d_p,
                                            const float* s_p, const float* inc_p,
                                            const float* bi_p, float* cs) {
  if (threadIdx.x == 0) {
    float bd = *bd_p, d = *d_p, s = *s_p, inc = *inc_p, bi = *bi_p;
    cs[0] = 0.0f;                                       // cat 0 (unused)
    cs[1] = fminf(bd, fminf(0.0f, d)) - EPS_C;          // big decrease
    cs[2] = fminf(fmaxf(d, bd + EPS_C), -EPS_C);        // decrease (clip)
    cs[3] = s;                                          // same
    cs[4] = fminf(fmaxf(inc, EPS_C), bi - EPS_C);       // increase (clip)
    cs[5] = fmaxf(bi, fmaxf(0.0f, inc) + EPS_C);        // big increase
    cs[6] = 0.0f; cs[7] = 0.0f;
  }
}

// Pass 1: per-block sum + re-pack categories to 4 bits/elem in global ws.
// Sub-tile j: thread t reads 4 consecutive int4 (64 B), emits one uint2.
__global__ __launch_bounds__(BLOCK) void k_reduce_pack(
    const int* __restrict__ ann, const float* bd, const float* d,
    const float* s, const float* inc, const float* bi,
    uint2* __restrict__ packed, float* __restrict__ sums) {
  __shared__ float cs[8];
  __shared__ float wsum[BLOCK / 64];
  build_table(bd, d, s, inc, bi, cs);
  __syncthreads();

  const int b = blockIdx.x, t = threadIdx.x;
  const int4* in4 = (const int4*)(ann + (size_t)b * CHUNK);

  float sum = 0.0f;
#pragma unroll
  for (int j = 0; j < SUBT; ++j) {
    unsigned int w0 = 0u, w1 = 0u;
#pragma unroll
    for (int i = 0; i < 4; ++i) {
      int4 v = in4[j * 1024 + t * 4 + i];
      sum += cs[v.x] + cs[v.y] + cs[v.z] + cs[v.w];
      unsigned int nib = (unsigned)v.x | ((unsigned)v.y << 4) |
                         ((unsigned)v.z << 8) | ((unsigned)v.w << 12);
      if (i < 2) w0 |= nib << ((i & 1) * 16);
      else       w1 |= nib << ((i & 1) * 16);
    }
    packed[(size_t)b * (SUBT * BLOCK) + j * BLOCK + t] = make_uint2(w0, w1);
  }

#pragma unroll
  for (int off = 32; off >= 1; off >>= 1) sum += __shfl_down(sum, off, 64);
  const int lane = t & 63, wid = t >> 6;
  if (lane == 0) wsum[wid] = sum;
  __syncthreads();
  if (t == 0) sums[b] = wsum[0] + wsum[1] + wsum[2] + wsum[3];
}

// Pass 2: block b reduces sums[0..b) for its offset (pack loads issued first,
// in flight during the reduce), decodes, block-scans, writes (plain cached
// stores — L2 merges the 16B/lane pattern into full lines; NT stores caused
// 2.5x write amplification in R6).
__global__ __launch_bounds__(BLOCK) void k_scan_out(
    const uint2* __restrict__ packed, const float* __restrict__ sums,
    const float* __restrict__ origin, const float* bd, const float* d,
    const float* s, const float* inc, const float* bi,
    float* __restrict__ out, int nb) {
  __shared__ float cs[8];
  __shared__ float wsum[BLOCK / 64];
  __shared__ float s_base;
  build_table(bd, d, s, inc, bi, cs);
  __syncthreads();

  const int b = blockIdx.x, t = threadIdx.x;
  const int lane = t & 63, wid = t >> 6;

  // Issue pack loads first so they're in flight during the sums reduce.
  uint2 w[SUBT];
#pragma unroll
  for (int j = 0; j < SUBT; ++j)
    w[j] = packed[(size_t)b * (SUBT * BLOCK) + j * BLOCK + t];

  // Block offset: reduce predecessor sums (<= nb/BLOCK = 16 iterations, L2-hot).
  float p = 0.0f;
  for (int i = t; i < b; i += BLOCK) p += sums[i];
#pragma unroll
  for (int off = 32; off >= 1; off >>= 1) p += __shfl_down(p, off, 64);
  if (lane == 0) wsum[wid] = p;
  __syncthreads();
  if (t == 0) s_base = *origin + wsum[0] + wsum[1] + wsum[2] + wsum[3];
  __syncthreads();

  float carry = s_base;
#pragma unroll
  for (int j = 0; j < SUBT; ++j) {
    // Decode 16 categories from one uint2.
    float vals[16];
#pragma unroll
    for (int k = 0; k < 8; ++k) vals[k] = cs[(w[j].x >> (4 * k)) & 0xF];
#pragma unroll
    for (int k = 0; k < 8; ++k) vals[8 + k] = cs[(w[j].y >> (4 * k)) & 0xF];

    float run = 0.0f;
#pragma unroll
    for (int i = 0; i < 16; ++i) run += vals[i];

    float x = run;  // inclusive wave scan of per-thread totals
#pragma unroll
    for (int off = 1; off < 64; off <<= 1) {
      float y = __shfl_up(x, off, 64);
      if (lane >= off) x += y;
    }
    __syncthreads();  // prior wsum/s_base reads are done
    if (lane == 63) wsum[wid] = x;
    __syncthreads();
    float wexcl = 0.0f, tot = 0.0f;
#pragma unroll
    for (int i = 0; i < BLOCK / 64; ++i) {
      float wv = wsum[i];
      if (i < wid) wexcl += wv;
      tot += wv;
    }
    const float off0 = carry + wexcl + (x - run);  // thread-exclusive prefix

    float4* out4 = (float4*)(out + (size_t)b * CHUNK + j * 4096);
    float r = off0;
#pragma unroll
    for (int i = 0; i < 4; ++i) {
      float4 o;
      o.x = r; r += vals[i * 4 + 0];
      o.y = r; r += vals[i * 4 + 1];
      o.z = r; r += vals[i * 4 + 2];
      o.w = r; r += vals[i * 4 + 3];
      out4[t * 4 + i] = o;
    }
    carry += tot;

    if (b == nb - 1 && t == BLOCK - 1 && j == SUBT - 1)
      out[(size_t)nb * CHUNK] = r;  // out[N] = origin + total sum
  }
}

extern "C" void kernel_launch(void* const* d_in, const int* in_sizes, int n_in,
                              void* d_out, int out_size, void* d_ws, size_t ws_size,
                              hipStream_t stream) {
  const int*   ann    = (const int*)d_in[0];
  const float* origin = (const float*)d_in[1];
  const float* bd     = (const float*)d_in[2];
  const float* dw     = (const float*)d_in[3];
  const float* sw     = (const float*)d_in[4];
  const float* inc    = (const float*)d_in[5];
  const float* bi     = (const float*)d_in[6];
  float* out = (float*)d_out;

  const int N  = in_sizes[0];   // 2^25, divisible by CHUNK
  const int nb = N / CHUNK;     // 4096

  float* sums   = (float*)d_ws;                      // nb floats (16 KB)
  uint2* packed = (uint2*)((char*)d_ws + 32768);     // nb*512 uint2 (16.8 MB)

  k_reduce_pack<<<nb, BLOCK, 0, stream>>>(ann, bd, dw, sw, inc, bi, packed, sums);
  k_scan_out<<<nb, BLOCK, 0, stream>>>(packed, sums, origin, bd, dw, sw, inc, bi,
                                       out, nb);
}

// Round 9
// 261.991 us; speedup vs baseline: 1.5663x; 1.0388x over previous
//
#include <hip/hip_runtime.h>

#define EPS_C 0.05f
#define BLOCK 256
#define SUBT 2
#define CHUNK (SUBT * 4096)   /* pass-1 block: 8192 elems, 32/thread */
#define CHUNK2 2048           /* pass-2 block: 2048 elems, 8/thread */

typedef int i4 __attribute__((ext_vector_type(4)));    /* nt-load-compatible */

// Build the 6-entry change table into LDS (thread 0 only; caller syncs).
__device__ __forceinline__ void build_table(const float* bd_p, const float* d_p,
                                            const float* s_p, const float* inc_p,
                                            const float* bi_p, float* cs) {
  if (threadIdx.x == 0) {
    float bd = *bd_p, d = *d_p, s = *s_p, inc = *inc_p, bi = *bi_p;
    cs[0] = 0.0f;                                       // cat 0 (unused)
    cs[1] = fminf(bd, fminf(0.0f, d)) - EPS_C;          // big decrease
    cs[2] = fminf(fmaxf(d, bd + EPS_C), -EPS_C);        // decrease (clip)
    cs[3] = s;                                          // same
    cs[4] = fminf(fmaxf(inc, EPS_C), bi - EPS_C);       // increase (clip)
    cs[5] = fmaxf(bi, fmaxf(0.0f, inc) + EPS_C);        // big increase
    cs[6] = 0.0f; cs[7] = 0.0f;
  }
}

// Pass 1: pack categories to 4b/elem (pack is nibble[e], element order) and
// emit per-1024-elem fine sums + per-block coarse sums. Input loads are
// nontemporal (read-once) to protect pack/L3 residency.
__global__ __launch_bounds__(BLOCK) void k_reduce_pack(
    const int* __restrict__ ann, const float* bd, const float* d,
    const float* s, const float* inc, const float* bi,
    uint2* __restrict__ packed, float* __restrict__ coarse,
    float* __restrict__ fine) {
  __shared__ float cs[8];
  __shared__ float wsum[SUBT * 4];
  build_table(bd, d, s, inc, bi, cs);
  __syncthreads();

  const int b = blockIdx.x, t = threadIdx.x;
  const int lane = t & 63, wid = t >> 6;
  const i4* in4 = (const i4*)(ann + (size_t)b * CHUNK);

#pragma unroll
  for (int j = 0; j < SUBT; ++j) {
    unsigned int w0 = 0u, w1 = 0u;
    float sum = 0.0f;
#pragma unroll
    for (int i = 0; i < 4; ++i) {
      i4 v = __builtin_nontemporal_load(&in4[j * 1024 + t * 4 + i]);
      sum += cs[v.x] + cs[v.y] + cs[v.z] + cs[v.w];
      unsigned int nib = (unsigned)v.x | ((unsigned)v.y << 4) |
                         ((unsigned)v.z << 8) | ((unsigned)v.w << 12);
      if (i < 2) w0 |= nib << ((i & 1) * 16);
      else       w1 |= nib << ((i & 1) * 16);
    }
    packed[(size_t)b * (SUBT * BLOCK) + j * BLOCK + t] = make_uint2(w0, w1);
    // wave sum = fine sum over this wave's 1024 contiguous elems of subtile j
#pragma unroll
    for (int off = 32; off >= 1; off >>= 1) sum += __shfl_down(sum, off, 64);
    if (lane == 0) {
      fine[b * (SUBT * 4) + j * 4 + wid] = sum;
      wsum[j * 4 + wid] = sum;
    }
  }
  __syncthreads();
  if (t == 0) {
    float tot = 0.0f;
#pragma unroll
    for (int i = 0; i < SUBT * 4; ++i) tot += wsum[i];
    coarse[b] = tot;
  }
}

// Pass 2: block b2 covers [b2*2048, +2048). Thread t owns 4 contiguous
// elems per round (one ushort of pack, one fully-coalesced float4 store:
// lanes contiguous -> 1 KiB full-line wave stores).
__global__ __launch_bounds__(BLOCK) void k_scan_out(
    const unsigned short* __restrict__ uspack, const float* __restrict__ coarse,
    const float* __restrict__ fine, const float* __restrict__ origin,
    const float* bd, const float* d, const float* s, const float* inc,
    const float* bi, float* __restrict__ out, int nb2, int nbc) {
  __shared__ float cs[8];
  __shared__ float wsum[BLOCK / 64];
  __shared__ float s_base;
  build_table(bd, d, s, inc, bi, cs);
  __syncthreads();

  const int b2 = blockIdx.x, t = threadIdx.x;
  const int lane = t & 63, wid = t >> 6;
  const int cb = b2 >> 2;                 // owning coarse (P1) block
  const int fcnt = 2 * (b2 & 3);          // fine entries before us in cb

  // Prefetch both rounds' pack ushorts (in flight during offset reduce).
  unsigned short us0 = uspack[(size_t)b2 * 512 + t];
  unsigned short us1 = uspack[(size_t)b2 * 512 + 256 + t];

  // Block offset: coarse[0..cb) (<=16 iters, L2/L3-hot) + fine[cb*8..+fcnt).
  float p = 0.0f;
  for (int i = t; i < cb; i += BLOCK) p += coarse[i];
  if (t < fcnt) p += fine[cb * 8 + t];
#pragma unroll
  for (int off = 32; off >= 1; off >>= 1) p += __shfl_down(p, off, 64);
  if (lane == 0) wsum[wid] = p;
  __syncthreads();
  if (t == 0) s_base = *origin + wsum[0] + wsum[1] + wsum[2] + wsum[3];
  __syncthreads();

  float carry = s_base;
  unsigned short usv[2] = {us0, us1};
#pragma unroll
  for (int r = 0; r < 2; ++r) {
    const unsigned short us = usv[r];
    float v0 = cs[us & 0xF], v1 = cs[(us >> 4) & 0xF];
    float v2 = cs[(us >> 8) & 0xF], v3 = cs[(us >> 12) & 0xF];
    float run = v0 + v1 + v2 + v3;

    float x = run;  // inclusive wave scan of per-thread totals
#pragma unroll
    for (int off = 1; off < 64; off <<= 1) {
      float y = __shfl_up(x, off, 64);
      if (lane >= off) x += y;
    }
    __syncthreads();  // prior wsum/s_base reads done
    if (lane == 63) wsum[wid] = x;
    __syncthreads();
    float wexcl = 0.0f, tot = 0.0f;
#pragma unroll
    for (int i = 0; i < BLOCK / 64; ++i) {
      float wv = wsum[i];
      if (i < wid) wexcl += wv;
      tot += wv;
    }
    const float off0 = carry + wexcl + (x - run);

    float4 o;
    o.x = off0;
    o.y = off0 + v0;
    o.z = off0 + v0 + v1;
    o.w = off0 + v0 + v1 + v2;
    ((float4*)(out + (size_t)b2 * CHUNK2 + r * 1024))[t] = o;
    carry += tot;

    if (b2 == nb2 - 1 && t == BLOCK - 1 && r == 1)
      out[(size_t)nb2 * CHUNK2] = off0 + run;  // out[N]
  }
}

extern "C" void kernel_launch(void* const* d_in, const int* in_sizes, int n_in,
                              void* d_out, int out_size, void* d_ws, size_t ws_size,
                              hipStream_t stream) {
  const int*   ann    = (const int*)d_in[0];
  const float* origin = (const float*)d_in[1];
  const float* bd     = (const float*)d_in[2];
  const float* dw     = (const float*)d_in[3];
  const float* sw     = (const float*)d_in[4];
  const float* inc    = (const float*)d_in[5];
  const float* bi     = (const float*)d_in[6];
  float* out = (float*)d_out;

  const int N   = in_sizes[0];    // 2^25
  const int nbc = N / CHUNK;      // 4096 coarse blocks
  const int nb2 = N / CHUNK2;     // 16384 scan blocks

  float* coarse = (float*)d_ws;                       // 4096 floats
  float* fine   = (float*)((char*)d_ws + 65536);      // 32768 floats (128 KB)
  uint2* packed = (uint2*)((char*)d_ws + 262144);     // 16.8 MB

  k_reduce_pack<<<nbc, BLOCK, 0, stream>>>(ann, bd, dw, sw, inc, bi,
                                           packed, coarse, fine);
  k_scan_out<<<nb2, BLOCK, 0, stream>>>((const unsigned short*)packed, coarse,
                                        fine, origin, bd, dw, sw, inc, bi,
                                        out, nb2, nbc);
}